// Round 7
// baseline (238.542 us; speedup 1.0000x reference)
//
#include <hip/hip_runtime.h>
#include <hip/hip_bf16.h>
#include <math.h>

// Problem constants (T=2048, B=2, C=1024, H=16, DK=64)
#define T_SEQ 2048
#define B_SZ 2
#define C_DIM 1024
#define H_HEADS 16
#define DKH 64
#define M_ROWS (T_SEQ * B_SZ)   // 4096 rows in (t,b) order — matches [T,B,C] flat layout

// log2(e)/8: Q projection pre-scale so softmax runs in exp2 domain
#define QSCALE 0.1803368801111204f

typedef __attribute__((ext_vector_type(8))) short bf16x8;   // 8 bf16 = 4 VGPRs (MFMA A/B frag)
typedef __attribute__((ext_vector_type(4))) float f32x4;    // MFMA C/D frag
typedef unsigned short ushort_t;

// ---- helpers ----------------------------------------------------------------

__device__ __forceinline__ ushort_t f2bf(float f) {
    unsigned u = __float_as_uint(f);
    u += 0x7fffu + ((u >> 16) & 1u);
    return (ushort_t)(u >> 16);
}

// packed f32x2 -> bf16x2
__device__ __forceinline__ unsigned pack2bf(float a, float b) {
#if __has_builtin(__builtin_amdgcn_cvt_pk_bf16_f32)
    typedef __attribute__((ext_vector_type(2))) __bf16 bf16x2_t;
    union { bf16x2_t v; unsigned u; } cv;
    cv.v = __builtin_amdgcn_cvt_pk_bf16_f32(a, b);
    return cv.u;
#else
    return (unsigned)f2bf(a) | ((unsigned)f2bf(b) << 16);
#endif
}

__device__ __forceinline__ void async_copy16(const void* g, void* l) {
    __builtin_amdgcn_global_load_lds(
        (const __attribute__((address_space(1))) void*)g,
        (__attribute__((address_space(3))) void*)l, 16, 0, 0);
}

// ---- kernel 1: fused prep — RoPE(q,k), value perm-cast, 4x weight cast ------
// blocks [0,8192): rope; [8192,12288): value perm; [12288,16384): weights
__global__ __launch_bounds__(256) void prep_all(
        const float* __restrict__ q, const float* __restrict__ k,
        const float* __restrict__ value,
        const float* __restrict__ Wq, const float* __restrict__ Wk,
        const float* __restrict__ Wv, const float* __restrict__ Wo,
        ushort_t* __restrict__ qb, ushort_t* __restrict__ kb,
        ushort_t* __restrict__ vb2,
        ushort_t* __restrict__ Wqb, ushort_t* __restrict__ Wkb,
        ushort_t* __restrict__ Wvb, ushort_t* __restrict__ Wob) {
    int bid = blockIdx.x;
    int tid = threadIdx.x;
    if (bid < 8192) {
        // RoPE on q,k + cast (rows t*2+b)
        int idx  = bid * 256 + tid;                 // [0, T*B*H*32)
        int j    = idx & 31;
        int rest = idx >> 5;                        // t*B*H + b*H + h
        int h    = rest & (H_HEADS - 1);
        int tb   = rest >> 4;                       // t*B + b
        int t    = tb >> 1;
        float inv = exp2f(-(float)j * 0.41524101186092034f);  // 10000^(-j/32)
        float ang = (float)t * inv;
        float s, c;
        sincosf(ang, &s, &c);
        int base = tb * C_DIM + h * DKH + j;
        float q1 = q[base], q2 = q[base + 32];
        float k1 = k[base], k2 = k[base + 32];
        qb[base]      = f2bf(q1 * c - q2 * s);
        qb[base + 32] = f2bf(q2 * c + q1 * s);
        kb[base]      = f2bf(k1 * c - k2 * s);
        kb[base + 32] = f2bf(k2 * c + k1 * s);
    } else if (bid < 12288) {
        // value cast with row de-interleave: out row = b*T+t
        int i   = (bid - 8192) * 256 + tid;         // float4 index over [4096][256]
        int c4  = i & 255;
        int row = i >> 8;                           // b*2048 + t
        int b   = row >> 11, t = row & 2047;
        float4 v = reinterpret_cast<const float4*>(value)[(t * 2 + b) * 256 + c4];
        ushort4 o;
        o.x = f2bf(v.x); o.y = f2bf(v.y); o.z = f2bf(v.z); o.w = f2bf(v.w);
        reinterpret_cast<ushort4*>(vb2)[i] = o;
    } else {
        // weight casts
        int r     = bid - 12288;                    // 0..4095
        int which = r >> 10;
        int i     = (r & 1023) * 256 + tid;
        const float* in = which == 0 ? Wq : which == 1 ? Wk : which == 2 ? Wv : Wo;
        ushort_t*   out = which == 0 ? Wqb : which == 1 ? Wkb : which == 2 ? Wvb : Wob;
        float4 v = reinterpret_cast<const float4*>(in)[i];
        ushort4 o;
        o.x = f2bf(v.x); o.y = f2bf(v.y); o.z = f2bf(v.z); o.w = f2bf(v.w);
        reinterpret_cast<ushort4*>(out)[i] = o;
    }
}

// ---- GEMM core: NT, 128x128 tile, 4 waves (256 thr), m97 2-barrier loop -----
// Round-14: the 128x64 GEMMs were LDS-read-pipe bound (10 ds_read_b128 per
// 8 MFMA per K-step; ~1920 LDS-cy vs 640 MFMA-cy per CU per step). 128x128
// tile with 4 waves each owning a 64x64 quadrant (acc[4][4]) gives 32 MFMA /
// 16 ds_read per K-step = 2.4x FLOP per LDS-cycle. Single-buffered 32 KB LDS,
// m97-verified 2-barrier structure (__syncthreads drains the DMA); stall
// covered by 3 co-resident blocks/CU (z-fused qkv launch).
// Numerics: identical K-order and MFMA shape as previous rounds -> bit-equal.
__device__ __forceinline__ void gemm_core(
        ushort_t* As, ushort_t* Bs,               // [128*64] shorts each
        const ushort_t* __restrict__ A, const ushort_t* __restrict__ W,
        const float* __restrict__ bias, void* __restrict__ Cout,
        int N, int K, float scale, int rowBase, int colBase,
        bool biasRow, bool bf16out) {
    const int tid  = threadIdx.x;
    const int lane = tid & 63;
    const int w    = tid >> 6;         // 0..3
    const int wr   = (w >> 1) * 64;    // wave's row quadrant
    const int wc   = (w & 1) * 64;     // wave's col quadrant
    const int m16  = lane & 15, quad = lane >> 4;
    const int r8   = lane >> 3, c8 = lane & 7;
    const int clog = c8 ^ r8;

    f32x4 acc[4][4];
#pragma unroll
    for (int mi = 0; mi < 4; mi++)
#pragma unroll
        for (int ni = 0; ni < 4; ni++) acc[mi][ni] = (f32x4){0.f, 0.f, 0.f, 0.f};

    for (int kt = 0; kt < K; kt += 64) {
        // stage A-tile [128][64] and B-tile [128][64]: 8 DMAs per wave
#pragma unroll
        for (int i = 0; i < 4; ++i) {
            int R = w * 32 + i * 8;
            async_copy16(A + (size_t)(rowBase + R + r8) * K + kt + clog * 8,
                         As + R * 64);
        }
#pragma unroll
        for (int i = 0; i < 4; ++i) {
            int R = w * 32 + i * 8;
            async_copy16(W + (size_t)(colBase + R + r8) * K + kt + clog * 8,
                         Bs + R * 64);
        }
        __syncthreads();   // implicit vmcnt(0) drain: tile ready
#pragma unroll
        for (int ks = 0; ks < 2; ++ks) {
            int lc = ks * 4 + quad;
            bf16x8 af[4];
#pragma unroll
            for (int mi = 0; mi < 4; mi++) {
                int R = wr + mi * 16 + m16;
                af[mi] = *reinterpret_cast<const bf16x8*>(
                    &As[R * 64 + ((lc ^ (R & 7)) << 3)]);
            }
            bf16x8 bfr[4];
#pragma unroll
            for (int ni = 0; ni < 4; ni++) {
                int R = wc + ni * 16 + m16;
                bfr[ni] = *reinterpret_cast<const bf16x8*>(
                    &Bs[R * 64 + ((lc ^ (R & 7)) << 3)]);
            }
#pragma unroll
            for (int mi = 0; mi < 4; mi++)
#pragma unroll
                for (int ni = 0; ni < 4; ni++)
                    acc[mi][ni] = __builtin_amdgcn_mfma_f32_16x16x32_bf16(
                        af[mi], bfr[ni], acc[mi][ni], 0, 0, 0);
        }
        __syncthreads();   // all reads in regs before next stage overwrites
    }
#pragma unroll
    for (int mi = 0; mi < 4; mi++)
#pragma unroll
        for (int ni = 0; ni < 4; ni++)
#pragma unroll
            for (int r = 0; r < 4; r++) {
                int row = rowBase + wr + mi * 16 + quad * 4 + r;
                int col = colBase + wc + ni * 16 + m16;
                float v = (acc[mi][ni][r] + (biasRow ? bias[row] : bias[col])) * scale;
                if (bf16out)
                    ((ushort_t*)Cout)[(size_t)row * N + col] = f2bf(v);
                else
                    ((float*)Cout)[(size_t)row * N + col] = v;
            }
}

// ---- kernel 2: fused QKV projections — grid (256, 3), 256 thr ---------------
// z=0: Q-proj (qb x Wq^T -> Qp, QSCALE), z=1: K-proj, z=2: V-GEMM
// (Wv x vb2^T -> VTg, bias over rows). 768 blocks = 3 blocks/CU co-resident
// (LDS 3x32=96 <= 160 KB) — stage-drain stalls hide across blocks/slices.
__global__ __launch_bounds__(256) void qkv_gemm(
        const ushort_t* __restrict__ qb, const ushort_t* __restrict__ kb,
        const ushort_t* __restrict__ Wqb, const ushort_t* __restrict__ Wkb,
        const ushort_t* __restrict__ Wvb, const ushort_t* __restrict__ vb2,
        const float* __restrict__ bq, const float* __restrict__ bk,
        const float* __restrict__ bv,
        ushort_t* __restrict__ Qp, ushort_t* __restrict__ Kp,
        ushort_t* __restrict__ VTg) {
    __shared__ ushort_t As[128 * 64];
    __shared__ ushort_t Bs[128 * 64];
    int z = blockIdx.y;
    const ushort_t* A; const ushort_t* W; const float* bias; ushort_t* C;
    int N, bx, by; bool biasRow; float scale;
    if (z == 0) {
        A = qb;  W = Wqb; bias = bq; C = Qp;  N = C_DIM;  biasRow = false;
        scale = QSCALE; bx = blockIdx.x & 7;  by = blockIdx.x >> 3;   // 8 x 32
    } else if (z == 1) {
        A = kb;  W = Wkb; bias = bk; C = Kp;  N = C_DIM;  biasRow = false;
        scale = 1.0f;   bx = blockIdx.x & 7;  by = blockIdx.x >> 3;   // 8 x 32
    } else {
        A = Wvb; W = vb2; bias = bv; C = VTg; N = M_ROWS; biasRow = true;
        scale = 1.0f;   bx = blockIdx.x & 31; by = blockIdx.x >> 5;   // 32 x 8
    }
    gemm_core(As, Bs, A, W, bias, C, N, C_DIM, scale,
              by * 128, bx * 128, biasRow, true);
}

// ---- kernel 3: output projection (fp32 out), 128x128, 256 blocks ------------
__global__ __launch_bounds__(256) void gemm_o(
        const ushort_t* __restrict__ Xb, const ushort_t* __restrict__ Wob,
        const float* __restrict__ bo, float* __restrict__ out) {
    __shared__ ushort_t As[128 * 64];
    __shared__ ushort_t Bs[128 * 64];
    gemm_core(As, Bs, Xb, Wob, bo, out, C_DIM, C_DIM, 1.0f,
              blockIdx.y * 128, blockIdx.x * 128, false, false);
}

// ---- kernel 4: flash attention (r11 verified 62 µs version, unchanged) ------
__global__ __launch_bounds__(256) void attn(
        const ushort_t* __restrict__ Qp, const ushort_t* __restrict__ Kp,
        const ushort_t* __restrict__ VTg, ushort_t* __restrict__ X) {
    __shared__ char smem[40960];
    ushort_t* Qt = (ushort_t*)smem;            // [64 q][64 dk]        8 KB
    char*  KtC   = smem + 8192;                // wave w: [32 key][64 dk] @ +w*4096
    char*  VTC   = smem + 24576;               // wave w: [64 dk][32 key] @ +w*4096
    float* exch  = (float*)(smem + 8192);      // epilogue O-exchange (32 KB)
    float* lbuf  = (float*)smem;               // epilogue l-exchange (1 KB, in Qt)

    const int tid  = threadIdx.x;
    const int lane = tid & 63;
    const int w    = tid >> 6;
    const int m16  = lane & 15, quad = lane >> 4;
    const int r8   = lane >> 3, c8 = lane & 7;
    const int clog = c8 ^ r8;

    // XCD-locality swizzle (bijection on 1024 block ids)
    const int lid   = blockIdx.x + blockIdx.y * 32;
    const int jj    = lid >> 3;
    const int pair  = (lid & 7) * 4 + (jj >> 5);   // b*H + h, constant per XCD group
    const int qBase = (jj & 31) * 64;
    const int b = pair >> 4, h = pair & 15;

    // hoisted loop-invariant LDS byte offsets
    const int ofA = m16 * 128 + ((quad ^ (m16 & 7)) << 4);        // ks=0, 128B rows
    const int ofB = m16 * 128 + (((4 + quad) ^ (m16 & 7)) << 4);  // ks=1
    const int sw4 = (m16 >> 1) & 3;                               // 64B-row swizzle
    const int fro = m16 * 64 + ((quad ^ sw4) << 4);               // pf/vf reads
    int pw0[2];
#pragma unroll
    for (int kt_i = 0; kt_i < 2; kt_i++)
        pw0[kt_i] = m16 * 64 + (((kt_i * 2 + (quad >> 1)) ^ sw4) << 4) + (quad & 1) * 8;
    char* PwC = KtC + w * 4096;     // P overlay on wave's own Kt quarter

    // V staging: DMA writes linearly (phys chunk = lane&3 of row lane>>2), so
    // pre-swizzle the GLOBAL source chunk: logical = phys ^ sw(row) = phys ^ ((row>>1)&3)
    const int vlc = (lane & 3) ^ ((lane >> 3) & 3);

    // ---- prologue: stage Q tile [64 q][64 dk], load ALL 64 q B-frags --------
#pragma unroll
    for (int i = 0; i < 2; ++i) {
        int R = w * 16 + i * 8;
        async_copy16(Qp + (size_t)((qBase + R + r8) * 2 + b) * C_DIM + h * DKH + clog * 8,
                     &Qt[R * 64]);
    }
    __syncthreads();
    bf16x8 aq[4][2];
#pragma unroll
    for (int ni = 0; ni < 4; ni++) {
        aq[ni][0] = *reinterpret_cast<const bf16x8*>((const char*)Qt + ni * 2048 + ofA);
        aq[ni][1] = *reinterpret_cast<const bf16x8*>((const char*)Qt + ni * 2048 + ofB);
    }
    asm volatile("s_waitcnt lgkmcnt(0)" ::: "memory");
    __syncthreads();

    float lrun[4] = {0.f, 0.f, 0.f, 0.f};
    f32x4 o[4][4];
#pragma unroll
    for (int mi = 0; mi < 4; mi++)
#pragma unroll
        for (int ni = 0; ni < 4; ni++) o[mi][ni] = (f32x4){0.f, 0.f, 0.f, 0.f};

    // stage K,V for the wave's quarter at k-tile kt
    auto stageKV = [&](int kt) {
#pragma unroll
        for (int i = 0; i < 4; ++i) {
            int key = kt + w * 32 + i * 8 + r8;
            async_copy16(Kp + (size_t)(key * 2 + b) * C_DIM + h * DKH + clog * 8,
                         KtC + w * 4096 + i * 1024);
        }
#pragma unroll
        for (int i = 0; i < 4; ++i) {
            int dkr = i * 16 + (lane >> 2);
            async_copy16(VTg + (size_t)(h * DKH + dkr) * M_ROWS + b * T_SEQ + kt + w * 32 + vlc * 8,
                         VTC + w * 4096 + i * 1024);
        }
    };

    // ---- barrier-free, software-pipelined main loop -------------------------
    stageKV(0);
    for (int kt = 0; kt < T_SEQ; kt += 128) {
        asm volatile("s_waitcnt vmcnt(0)" ::: "memory");
        __builtin_amdgcn_sched_barrier(0);

        // S^T = K·Q^T over wave's 32 keys x 64 q (log2 domain)
        f32x4 s[2][4];
#pragma unroll
        for (int kt_i = 0; kt_i < 2; kt_i++) {
#pragma unroll
            for (int ni = 0; ni < 4; ni++) s[kt_i][ni] = (f32x4){0.f, 0.f, 0.f, 0.f};
            bf16x8 kf0 = *reinterpret_cast<const bf16x8*>(KtC + w * 4096 + kt_i * 2048 + ofA);
            bf16x8 kf1 = *reinterpret_cast<const bf16x8*>(KtC + w * 4096 + kt_i * 2048 + ofB);
#pragma unroll
            for (int ni = 0; ni < 4; ni++) {
                s[kt_i][ni] = __builtin_amdgcn_mfma_f32_16x16x32_bf16(kf0, aq[ni][0], s[kt_i][ni], 0, 0, 0);
                s[kt_i][ni] = __builtin_amdgcn_mfma_f32_16x16x32_bf16(kf1, aq[ni][1], s[kt_i][ni], 0, 0, 0);
            }
        }

        // p = exp2(s); accumulate l; write P (bf16) into wave-private overlay
#pragma unroll
        for (int kt_i = 0; kt_i < 2; kt_i++)
#pragma unroll
            for (int ni = 0; ni < 4; ni++) {
                float p0 = __builtin_amdgcn_exp2f(s[kt_i][ni][0]);
                float p1 = __builtin_amdgcn_exp2f(s[kt_i][ni][1]);
                float p2 = __builtin_amdgcn_exp2f(s[kt_i][ni][2]);
                float p3 = __builtin_amdgcn_exp2f(s[kt_i][ni][3]);
                lrun[ni] += (p0 + p1) + (p2 + p3);
                uint2 pv;
                pv.x = pack2bf(p0, p1);
                pv.y = pack2bf(p2, p3);
                *reinterpret_cast<uint2*>(PwC + ni * 1024 + pw0[kt_i]) = pv;
            }
        asm volatile("s_waitcnt lgkmcnt(0)" ::: "memory");

        // pf/vf into regs, then quarters are dead -> prefetch next k-tile
        bf16x8 pf[4];
#pragma unroll
        for (int ni = 0; ni < 4; ni++)
            pf[ni] = *reinterpret_cast<const bf16x8*>(PwC + ni * 1024 + fro);
        bf16x8 vfr[4];
#pragma unroll
        for (int mi = 0; mi < 4; mi++)
            vfr[mi] = *reinterpret_cast<const bf16x8*>(VTC + w * 4096 + mi * 1024 + fro);
        asm volatile("s_waitcnt lgkmcnt(0)" ::: "memory");
        __builtin_amdgcn_sched_barrier(0);
        if (kt + 128 < T_SEQ) stageKV(kt + 128);
        __builtin_amdgcn_sched_barrier(0);

        // O^T += V^T·P^T (pure-register; DMA for next tile flies underneath)
#pragma unroll
        for (int mi = 0; mi < 4; mi++)
#pragma unroll
            for (int ni = 0; ni < 4; ni++)
                o[mi][ni] = __builtin_amdgcn_mfma_f32_16x16x32_bf16(vfr[mi], pf[ni], o[mi][ni], 0, 0, 0);
    }

    // ---- epilogue: cross-wave l and O reduction -----------------------------
#pragma unroll
    for (int ni = 0; ni < 4; ni++) {
        lrun[ni] += __shfl_xor(lrun[ni], 16);
        lrun[ni] += __shfl_xor(lrun[ni], 32);
    }
    float lv = quad == 0 ? lrun[0] : quad == 1 ? lrun[1] : quad == 2 ? lrun[2] : lrun[3];
    lbuf[w * 64 + quad * 16 + m16] = lv;

    __syncthreads();   // all waves out of k-loop before exch overlays staging

    // O exchange in 2 rounds over the now-dead Kt+VT region (32 KB)
#pragma unroll
    for (int rnd = 0; rnd < 2; rnd++) {
        if (rnd) __syncthreads();
#pragma unroll
        for (int t2 = 0; t2 < 2; t2++) {
            int mi = 2 * rnd + t2;
#pragma unroll
            for (int ni = 0; ni < 4; ni++) {
                int q = ni * 16 + m16;
                int cw = t2 * 4 + quad;
                *reinterpret_cast<f32x4*>(
                    &exch[w * 2048 + q * 32 + ((cw ^ (q & 7)) << 2)]) = o[mi][ni];
            }
        }
        __syncthreads();
        int q = tid >> 2;
        float lsum = lbuf[q] + lbuf[64 + q] + lbuf[128 + q] + lbuf[192 + q];
        float invl = 1.0f / lsum;
#pragma unroll
        for (int half = 0; half < 2; half++) {
            int c = (tid & 3) + 4 * half;
            int off = q * 32 + (((c ^ (q & 7))) << 2);
            f32x4 v = *reinterpret_cast<const f32x4*>(&exch[off]);
            f32x4 v1 = *reinterpret_cast<const f32x4*>(&exch[2048 + off]);
            f32x4 v2 = *reinterpret_cast<const f32x4*>(&exch[4096 + off]);
            f32x4 v3 = *reinterpret_cast<const f32x4*>(&exch[6144 + off]);
            v = v + v1 + v2 + v3;
            uint2 pk;
            pk.x = pack2bf(v[0] * invl, v[1] * invl);
            pk.y = pack2bf(v[2] * invl, v[3] * invl);
            int t = qBase + q;
            *reinterpret_cast<uint2*>(
                &X[(size_t)(t * 2 + b) * C_DIM + h * DKH + rnd * 32 + c * 4]) = pk;
        }
    }
}

// ---- launch -----------------------------------------------------------------
extern "C" void kernel_launch(void* const* d_in, const int* in_sizes, int n_in,
                              void* d_out, int out_size, void* d_ws, size_t ws_size,
                              hipStream_t stream) {
    const float* query = (const float*)d_in[0];
    const float* key   = (const float*)d_in[1];
    const float* value = (const float*)d_in[2];
    const float* Wq = (const float*)d_in[3];
    const float* bq = (const float*)d_in[4];
    const float* Wk = (const float*)d_in[5];
    const float* bk = (const float*)d_in[6];
    const float* Wv = (const float*)d_in[7];
    const float* bv = (const float*)d_in[8];
    const float* Wo = (const float*)d_in[9];
    const float* bo = (const float*)d_in[10];
    float* out = (float*)d_out;

    ushort_t* qb  = (ushort_t*)d_ws;                    // [4096][1024] rows t*2+b
    ushort_t* kb  = qb  + (size_t)M_ROWS * C_DIM;
    ushort_t* vb2 = kb  + (size_t)M_ROWS * C_DIM;       // [4096][1024] rows b*T+t
    ushort_t* Wqb = vb2 + (size_t)M_ROWS * C_DIM;
    ushort_t* Wkb = Wqb + (size_t)C_DIM * C_DIM;
    ushort_t* Wvb = Wkb + (size_t)C_DIM * C_DIM;
    ushort_t* Wob = Wvb + (size_t)C_DIM * C_DIM;
    ushort_t* Qp  = Wob + (size_t)C_DIM * C_DIM;        // [4096][1024] rows t*2+b
    ushort_t* Kp  = Qp  + (size_t)M_ROWS * C_DIM;
    ushort_t* VTg = Kp  + (size_t)M_ROWS * C_DIM;       // [1024][4096] cols b*T+t
    ushort_t* Xb  = VTg + (size_t)M_ROWS * C_DIM;       // [4096][1024] rows t*2+b

    // 1) fused prep: RoPE + value perm + weight casts (one launch)
    prep_all<<<16384, 256, 0, stream>>>(query, key, value, Wq, Wk, Wv, Wo,
                                        qb, kb, vb2, Wqb, Wkb, Wvb, Wob);

    // 2) fused QKV projections (one launch, 768 blocks = 3 blocks/CU)
    qkv_gemm<<<dim3(256, 3), 256, 0, stream>>>(qb, kb, Wqb, Wkb, Wvb, vb2,
                                               bq, bk, bv, Qp, Kp, VTg);

    // 3) flash attention (r11 verified 62 µs version)
    attn<<<dim3(T_SEQ / 64, B_SZ * H_HEADS), 256, 0, stream>>>(Qp, Kp, VTg, Xb);

    // 4) output projection -> fp32 d_out (128x128 tiles, 256 blocks)
    gemm_o<<<dim3(C_DIM / 128, M_ROWS / 128), 256, 0, stream>>>(Xb, Wob, bo, out);
}

// Round 8
// 229.568 us; speedup vs baseline: 1.0391x; 1.0391x over previous
//
#include <hip/hip_runtime.h>
#include <hip/hip_bf16.h>
#include <math.h>

// Problem constants (T=2048, B=2, C=1024, H=16, DK=64)
#define T_SEQ 2048
#define B_SZ 2
#define C_DIM 1024
#define H_HEADS 16
#define DKH 64
#define M_ROWS (T_SEQ * B_SZ)   // 4096 rows in (t,b) order — matches [T,B,C] flat layout

// log2(e)/8: Q projection pre-scale so softmax runs in exp2 domain
#define QSCALE 0.1803368801111204f

typedef __attribute__((ext_vector_type(8))) short bf16x8;   // 8 bf16 = 4 VGPRs (MFMA A/B frag)
typedef __attribute__((ext_vector_type(4))) float f32x4;    // MFMA C/D frag
typedef unsigned short ushort_t;

// ---- helpers ----------------------------------------------------------------

__device__ __forceinline__ ushort_t f2bf(float f) {
    unsigned u = __float_as_uint(f);
    u += 0x7fffu + ((u >> 16) & 1u);
    return (ushort_t)(u >> 16);
}

// packed f32x2 -> bf16x2
__device__ __forceinline__ unsigned pack2bf(float a, float b) {
#if __has_builtin(__builtin_amdgcn_cvt_pk_bf16_f32)
    typedef __attribute__((ext_vector_type(2))) __bf16 bf16x2_t;
    union { bf16x2_t v; unsigned u; } cv;
    cv.v = __builtin_amdgcn_cvt_pk_bf16_f32(a, b);
    return cv.u;
#else
    return (unsigned)f2bf(a) | ((unsigned)f2bf(b) << 16);
#endif
}

__device__ __forceinline__ void async_copy16(const void* g, void* l) {
    __builtin_amdgcn_global_load_lds(
        (const __attribute__((address_space(1))) void*)g,
        (__attribute__((address_space(3))) void*)l, 16, 0, 0);
}

// ---- kernel 1: fused prep — RoPE(q,k), value perm-cast, 4x weight cast ------
// blocks [0,8192): rope; [8192,12288): value perm; [12288,16384): weights
__global__ __launch_bounds__(256) void prep_all(
        const float* __restrict__ q, const float* __restrict__ k,
        const float* __restrict__ value,
        const float* __restrict__ Wq, const float* __restrict__ Wk,
        const float* __restrict__ Wv, const float* __restrict__ Wo,
        ushort_t* __restrict__ qb, ushort_t* __restrict__ kb,
        ushort_t* __restrict__ vb2,
        ushort_t* __restrict__ Wqb, ushort_t* __restrict__ Wkb,
        ushort_t* __restrict__ Wvb, ushort_t* __restrict__ Wob) {
    int bid = blockIdx.x;
    int tid = threadIdx.x;
    if (bid < 8192) {
        // RoPE on q,k + cast (rows t*2+b)
        int idx  = bid * 256 + tid;                 // [0, T*B*H*32)
        int j    = idx & 31;
        int rest = idx >> 5;                        // t*B*H + b*H + h
        int h    = rest & (H_HEADS - 1);
        int tb   = rest >> 4;                       // t*B + b
        int t    = tb >> 1;
        float inv = exp2f(-(float)j * 0.41524101186092034f);  // 10000^(-j/32)
        float ang = (float)t * inv;
        float s, c;
        sincosf(ang, &s, &c);
        int base = tb * C_DIM + h * DKH + j;
        float q1 = q[base], q2 = q[base + 32];
        float k1 = k[base], k2 = k[base + 32];
        qb[base]      = f2bf(q1 * c - q2 * s);
        qb[base + 32] = f2bf(q2 * c + q1 * s);
        kb[base]      = f2bf(k1 * c - k2 * s);
        kb[base + 32] = f2bf(k2 * c + k1 * s);
    } else if (bid < 12288) {
        // value cast with row de-interleave: out row = b*T+t
        int i   = (bid - 8192) * 256 + tid;         // float4 index over [4096][256]
        int c4  = i & 255;
        int row = i >> 8;                           // b*2048 + t
        int b   = row >> 11, t = row & 2047;
        float4 v = reinterpret_cast<const float4*>(value)[(t * 2 + b) * 256 + c4];
        ushort4 o;
        o.x = f2bf(v.x); o.y = f2bf(v.y); o.z = f2bf(v.z); o.w = f2bf(v.w);
        reinterpret_cast<ushort4*>(vb2)[i] = o;
    } else {
        // weight casts
        int r     = bid - 12288;                    // 0..4095
        int which = r >> 10;
        int i     = (r & 1023) * 256 + tid;
        const float* in = which == 0 ? Wq : which == 1 ? Wk : which == 2 ? Wv : Wo;
        ushort_t*   out = which == 0 ? Wqb : which == 1 ? Wkb : which == 2 ? Wvb : Wob;
        float4 v = reinterpret_cast<const float4*>(in)[i];
        ushort4 o;
        o.x = f2bf(v.x); o.y = f2bf(v.y); o.z = f2bf(v.z); o.w = f2bf(v.w);
        reinterpret_cast<ushort4*>(out)[i] = o;
    }
}

// ---- kernel 2: fused QKV projections — 256x64 tile, 8 waves, single-buf -----
// Round-15: intensity upgrade WITHOUT losing TLP (the r4/r5/r7 failure mode).
// 256x64 tile, 8 waves as 4x2 (wave owns 64 rows x 32 cols, acc[4][2]):
// per K-step per wave 16 MFMA / 12 ds_read (1.67x r6's 8/10) at the SAME
// 24 waves/CU (3 blocks x 8 waves; LDS 40 KB single-buf, 3x40=120<=160).
// m97 2-barrier loop (syncthreads drains DMA); drain covered by 3 blocks/CU.
__global__ __launch_bounds__(512) void qkv_gemm(
        const ushort_t* __restrict__ qb, const ushort_t* __restrict__ kb,
        const ushort_t* __restrict__ Wqb, const ushort_t* __restrict__ Wkb,
        const ushort_t* __restrict__ Wvb, const ushort_t* __restrict__ vb2,
        const float* __restrict__ bq, const float* __restrict__ bk,
        const float* __restrict__ bv,
        ushort_t* __restrict__ Qp, ushort_t* __restrict__ Kp,
        ushort_t* __restrict__ VTg) {
    __shared__ ushort_t As[256 * 64];   // 32 KB
    __shared__ ushort_t Bs[64 * 64];    //  8 KB
    int z = blockIdx.y;
    const ushort_t* A; const ushort_t* W; const float* bias; ushort_t* C;
    int N, bx, by; bool biasRow; float scale;
    if (z == 0) {
        A = qb;  W = Wqb; bias = bq; C = Qp;  N = C_DIM;  biasRow = false;
        scale = QSCALE; bx = blockIdx.x & 15; by = blockIdx.x >> 4;   // 16 x 16
    } else if (z == 1) {
        A = kb;  W = Wkb; bias = bk; C = Kp;  N = C_DIM;  biasRow = false;
        scale = 1.0f;   bx = blockIdx.x & 15; by = blockIdx.x >> 4;   // 16 x 16
    } else {
        A = Wvb; W = vb2; bias = bv; C = VTg; N = M_ROWS; biasRow = true;
        scale = 1.0f;   bx = blockIdx.x & 63; by = blockIdx.x >> 6;   // 64 x 4
    }
    const int K = C_DIM;
    const int tid  = threadIdx.x;
    const int lane = tid & 63;
    const int w    = tid >> 6;         // 0..7
    const int wr   = (w >> 1) * 64;    // wave row group (4 groups of 64)
    const int wc   = (w & 1) * 32;     // wave col group (2 groups of 32)
    const int m16  = lane & 15, quad = lane >> 4;
    const int r8   = lane >> 3, c8 = lane & 7;
    const int clog = c8 ^ r8;
    const int rowBase = by * 256;
    const int colBase = bx * 64;

    f32x4 acc[4][2];
#pragma unroll
    for (int mi = 0; mi < 4; mi++)
#pragma unroll
        for (int ni = 0; ni < 2; ni++) acc[mi][ni] = (f32x4){0.f, 0.f, 0.f, 0.f};

    for (int kt = 0; kt < K; kt += 64) {
        // stage: As 256 rows (4 x 8 per wave), Bs 64 rows (1 x 8 per wave)
#pragma unroll
        for (int i = 0; i < 4; ++i) {
            int R = w * 32 + i * 8;
            async_copy16(A + (size_t)(rowBase + R + r8) * K + kt + clog * 8,
                         As + R * 64);
        }
        {
            int R = w * 8;
            async_copy16(W + (size_t)(colBase + R + r8) * K + kt + clog * 8,
                         Bs + R * 64);
        }
        __syncthreads();   // drains vmcnt(0): tile ready
#pragma unroll
        for (int ks = 0; ks < 2; ++ks) {
            int lc = ks * 4 + quad;
            bf16x8 af[4];
#pragma unroll
            for (int mi = 0; mi < 4; mi++) {
                int R = wr + mi * 16 + m16;
                af[mi] = *reinterpret_cast<const bf16x8*>(
                    &As[R * 64 + ((lc ^ (R & 7)) << 3)]);
            }
            bf16x8 bfr[2];
#pragma unroll
            for (int ni = 0; ni < 2; ni++) {
                int R = wc + ni * 16 + m16;
                bfr[ni] = *reinterpret_cast<const bf16x8*>(
                    &Bs[R * 64 + ((lc ^ (R & 7)) << 3)]);
            }
#pragma unroll
            for (int mi = 0; mi < 4; mi++)
#pragma unroll
                for (int ni = 0; ni < 2; ni++)
                    acc[mi][ni] = __builtin_amdgcn_mfma_f32_16x16x32_bf16(
                        af[mi], bfr[ni], acc[mi][ni], 0, 0, 0);
        }
        __syncthreads();   // reads in regs before next stage overwrites
    }
#pragma unroll
    for (int mi = 0; mi < 4; mi++)
#pragma unroll
        for (int ni = 0; ni < 2; ni++)
#pragma unroll
            for (int r = 0; r < 4; r++) {
                int row = rowBase + wr + mi * 16 + quad * 4 + r;
                int col = colBase + wc + ni * 16 + m16;
                float v = (acc[mi][ni][r] + (biasRow ? bias[row] : bias[col])) * scale;
                C[(size_t)row * N + col] = f2bf(v);
            }
}

// ---- kernel 3: output projection — r6 verified 128x64 8-wave dbuf core ------
__global__ __launch_bounds__(512) void gemm_o(
        const ushort_t* __restrict__ Xb, const ushort_t* __restrict__ Wob,
        const float* __restrict__ bo, float* __restrict__ out) {
    __shared__ ushort_t As[2][128 * 64];
    __shared__ ushort_t Bs[2][64 * 64];
    const int K = C_DIM, N = C_DIM;
    const int tid  = threadIdx.x;
    const int lane = tid & 63;
    const int w    = tid >> 6;         // 0..7
    const int m16  = lane & 15, quad = lane >> 4;
    const int r8   = lane >> 3, c8 = lane & 7;
    const int clog = c8 ^ r8;
    const int rowBase = blockIdx.y * 128;
    const int colBase = blockIdx.x * 64;

    f32x4 acc[4];
#pragma unroll
    for (int j = 0; j < 4; j++) acc[j] = (f32x4){0.f, 0.f, 0.f, 0.f};

    auto stage = [&](int buf, int kt) {
#pragma unroll
        for (int i = 0; i < 2; ++i) {
            int R = w * 16 + i * 8;
            async_copy16(Xb + (size_t)(rowBase + R + r8) * K + kt + clog * 8,
                         &As[buf][R * 64]);
        }
        {
            int R = w * 8;
            async_copy16(Wob + (size_t)(colBase + R + r8) * K + kt + clog * 8,
                         &Bs[buf][R * 64]);
        }
    };

    stage(0, 0);
    int cur = 0;
    for (int kt = 0; kt < K; kt += 64, cur ^= 1) {
        if (kt + 64 < K) {
            stage(cur ^ 1, kt + 64);
            asm volatile("s_waitcnt vmcnt(3)" ::: "memory");
        } else {
            asm volatile("s_waitcnt vmcnt(0)" ::: "memory");
        }
        __builtin_amdgcn_s_barrier();
        __builtin_amdgcn_sched_barrier(0);
        const ushort_t* Asc = As[cur];
        const ushort_t* Bsc = Bs[cur];
#pragma unroll
        for (int ks = 0; ks < 2; ++ks) {
            int lc = ks * 4 + quad;
            bf16x8 af;
            {
                int R = w * 16 + m16;
                af = *reinterpret_cast<const bf16x8*>(
                    &Asc[R * 64 + ((lc ^ (R & 7)) << 3)]);
            }
            bf16x8 bfr[4];
#pragma unroll
            for (int ni = 0; ni < 4; ni++) {
                int R = ni * 16 + m16;
                bfr[ni] = *reinterpret_cast<const bf16x8*>(
                    &Bsc[R * 64 + ((lc ^ (R & 7)) << 3)]);
            }
#pragma unroll
            for (int ni = 0; ni < 4; ni++)
                acc[ni] = __builtin_amdgcn_mfma_f32_16x16x32_bf16(
                    af, bfr[ni], acc[ni], 0, 0, 0);
        }
        __builtin_amdgcn_s_barrier();
    }
#pragma unroll
    for (int ni = 0; ni < 4; ni++)
#pragma unroll
        for (int r = 0; r < 4; r++) {
            int row = rowBase + w * 16 + quad * 4 + r;
            int col = colBase + ni * 16 + m16;
            out[(size_t)row * N + col] = acc[ni][r] + bo[col];
        }
}

// ---- kernel 4: flash attention ----------------------------------------------
// Round-15 change (bounded): V-early read + split staging. vfr is read FIRST
// (V quarter dead immediately), V-stage issued before QK^T -> V's DMA covered
// by the whole iteration; K-stage stays after pf (P overlays K). Top-of-loop
// vmcnt(0) then only exposes K's 4 late DMAs (was all 8). Cost: vfr live
// across the iter, +16 VGPR (112 -> ~128; at >128 occupancy drops -> revert).
__global__ __launch_bounds__(256) void attn(
        const ushort_t* __restrict__ Qp, const ushort_t* __restrict__ Kp,
        const ushort_t* __restrict__ VTg, ushort_t* __restrict__ X) {
    __shared__ char smem[40960];
    ushort_t* Qt = (ushort_t*)smem;            // [64 q][64 dk]        8 KB
    char*  KtC   = smem + 8192;                // wave w: [32 key][64 dk] @ +w*4096
    char*  VTC   = smem + 24576;               // wave w: [64 dk][32 key] @ +w*4096
    float* exch  = (float*)(smem + 8192);      // epilogue O-exchange (32 KB)
    float* lbuf  = (float*)smem;               // epilogue l-exchange (1 KB, in Qt)

    const int tid  = threadIdx.x;
    const int lane = tid & 63;
    const int w    = tid >> 6;
    const int m16  = lane & 15, quad = lane >> 4;
    const int r8   = lane >> 3, c8 = lane & 7;
    const int clog = c8 ^ r8;

    // XCD-locality swizzle (bijection on 1024 block ids)
    const int lid   = blockIdx.x + blockIdx.y * 32;
    const int jj    = lid >> 3;
    const int pair  = (lid & 7) * 4 + (jj >> 5);   // b*H + h, constant per XCD group
    const int qBase = (jj & 31) * 64;
    const int b = pair >> 4, h = pair & 15;

    // hoisted loop-invariant LDS byte offsets
    const int ofA = m16 * 128 + ((quad ^ (m16 & 7)) << 4);        // ks=0, 128B rows
    const int ofB = m16 * 128 + (((4 + quad) ^ (m16 & 7)) << 4);  // ks=1
    const int sw4 = (m16 >> 1) & 3;                               // 64B-row swizzle
    const int fro = m16 * 64 + ((quad ^ sw4) << 4);               // pf/vf reads
    int pw0[2];
#pragma unroll
    for (int kt_i = 0; kt_i < 2; kt_i++)
        pw0[kt_i] = m16 * 64 + (((kt_i * 2 + (quad >> 1)) ^ sw4) << 4) + (quad & 1) * 8;
    char* PwC = KtC + w * 4096;     // P overlay on wave's own Kt quarter

    // V staging: DMA writes linearly (phys chunk = lane&3 of row lane>>2), so
    // pre-swizzle the GLOBAL source chunk: logical = phys ^ sw(row) = phys ^ ((row>>1)&3)
    const int vlc = (lane & 3) ^ ((lane >> 3) & 3);

    // ---- prologue: stage Q tile [64 q][64 dk], load ALL 64 q B-frags --------
#pragma unroll
    for (int i = 0; i < 2; ++i) {
        int R = w * 16 + i * 8;
        async_copy16(Qp + (size_t)((qBase + R + r8) * 2 + b) * C_DIM + h * DKH + clog * 8,
                     &Qt[R * 64]);
    }
    __syncthreads();
    bf16x8 aq[4][2];
#pragma unroll
    for (int ni = 0; ni < 4; ni++) {
        aq[ni][0] = *reinterpret_cast<const bf16x8*>((const char*)Qt + ni * 2048 + ofA);
        aq[ni][1] = *reinterpret_cast<const bf16x8*>((const char*)Qt + ni * 2048 + ofB);
    }
    asm volatile("s_waitcnt lgkmcnt(0)" ::: "memory");
    __syncthreads();

    float lrun[4] = {0.f, 0.f, 0.f, 0.f};
    f32x4 o[4][4];
#pragma unroll
    for (int mi = 0; mi < 4; mi++)
#pragma unroll
        for (int ni = 0; ni < 4; ni++) o[mi][ni] = (f32x4){0.f, 0.f, 0.f, 0.f};

    // split staging: K quarter (4 DMAs) / V quarter (4 DMAs)
    auto stageK = [&](int kt) {
#pragma unroll
        for (int i = 0; i < 4; ++i) {
            int key = kt + w * 32 + i * 8 + r8;
            async_copy16(Kp + (size_t)(key * 2 + b) * C_DIM + h * DKH + clog * 8,
                         KtC + w * 4096 + i * 1024);
        }
    };
    auto stageV = [&](int kt) {
#pragma unroll
        for (int i = 0; i < 4; ++i) {
            int dkr = i * 16 + (lane >> 2);
            async_copy16(VTg + (size_t)(h * DKH + dkr) * M_ROWS + b * T_SEQ + kt + w * 32 + vlc * 8,
                         VTC + w * 4096 + i * 1024);
        }
    };

    // ---- barrier-free, software-pipelined main loop -------------------------
    stageK(0); stageV(0);
    for (int kt = 0; kt < T_SEQ; kt += 128) {
        asm volatile("s_waitcnt vmcnt(0)" ::: "memory");
        __builtin_amdgcn_sched_barrier(0);

        // V-early: read vfr first, then restage V under the whole iteration
        bf16x8 vfr[4];
#pragma unroll
        for (int mi = 0; mi < 4; mi++)
            vfr[mi] = *reinterpret_cast<const bf16x8*>(VTC + w * 4096 + mi * 1024 + fro);
        asm volatile("s_waitcnt lgkmcnt(0)" ::: "memory");
        __builtin_amdgcn_sched_barrier(0);
        if (kt + 128 < T_SEQ) stageV(kt + 128);

        // S^T = K·Q^T over wave's 32 keys x 64 q (log2 domain)
        f32x4 s[2][4];
#pragma unroll
        for (int kt_i = 0; kt_i < 2; kt_i++) {
#pragma unroll
            for (int ni = 0; ni < 4; ni++) s[kt_i][ni] = (f32x4){0.f, 0.f, 0.f, 0.f};
            bf16x8 kf0 = *reinterpret_cast<const bf16x8*>(KtC + w * 4096 + kt_i * 2048 + ofA);
            bf16x8 kf1 = *reinterpret_cast<const bf16x8*>(KtC + w * 4096 + kt_i * 2048 + ofB);
#pragma unroll
            for (int ni = 0; ni < 4; ni++) {
                s[kt_i][ni] = __builtin_amdgcn_mfma_f32_16x16x32_bf16(kf0, aq[ni][0], s[kt_i][ni], 0, 0, 0);
                s[kt_i][ni] = __builtin_amdgcn_mfma_f32_16x16x32_bf16(kf1, aq[ni][1], s[kt_i][ni], 0, 0, 0);
            }
        }

        // p = exp2(s); accumulate l; write P (bf16) into wave-private overlay
#pragma unroll
        for (int kt_i = 0; kt_i < 2; kt_i++)
#pragma unroll
            for (int ni = 0; ni < 4; ni++) {
                float p0 = __builtin_amdgcn_exp2f(s[kt_i][ni][0]);
                float p1 = __builtin_amdgcn_exp2f(s[kt_i][ni][1]);
                float p2 = __builtin_amdgcn_exp2f(s[kt_i][ni][2]);
                float p3 = __builtin_amdgcn_exp2f(s[kt_i][ni][3]);
                lrun[ni] += (p0 + p1) + (p2 + p3);
                uint2 pv;
                pv.x = pack2bf(p0, p1);
                pv.y = pack2bf(p2, p3);
                *reinterpret_cast<uint2*>(PwC + ni * 1024 + pw0[kt_i]) = pv;
            }
        asm volatile("s_waitcnt lgkmcnt(0)" ::: "memory");

        // pf into regs; P (K overlay) consumed -> restage K under PV
        bf16x8 pf[4];
#pragma unroll
        for (int ni = 0; ni < 4; ni++)
            pf[ni] = *reinterpret_cast<const bf16x8*>(PwC + ni * 1024 + fro);
        asm volatile("s_waitcnt lgkmcnt(0)" ::: "memory");
        __builtin_amdgcn_sched_barrier(0);
        if (kt + 128 < T_SEQ) stageK(kt + 128);
        __builtin_amdgcn_sched_barrier(0);

        // O^T += V^T·P^T (pure-register; K DMAs fly underneath)
#pragma unroll
        for (int mi = 0; mi < 4; mi++)
#pragma unroll
            for (int ni = 0; ni < 4; ni++)
                o[mi][ni] = __builtin_amdgcn_mfma_f32_16x16x32_bf16(vfr[mi], pf[ni], o[mi][ni], 0, 0, 0);
    }

    // ---- epilogue: cross-wave l and O reduction -----------------------------
#pragma unroll
    for (int ni = 0; ni < 4; ni++) {
        lrun[ni] += __shfl_xor(lrun[ni], 16);
        lrun[ni] += __shfl_xor(lrun[ni], 32);
    }
    float lv = quad == 0 ? lrun[0] : quad == 1 ? lrun[1] : quad == 2 ? lrun[2] : lrun[3];
    lbuf[w * 64 + quad * 16 + m16] = lv;

    __syncthreads();   // all waves out of k-loop before exch overlays staging

    // O exchange in 2 rounds over the now-dead Kt+VT region (32 KB)
#pragma unroll
    for (int rnd = 0; rnd < 2; rnd++) {
        if (rnd) __syncthreads();
#pragma unroll
        for (int t2 = 0; t2 < 2; t2++) {
            int mi = 2 * rnd + t2;
#pragma unroll
            for (int ni = 0; ni < 4; ni++) {
                int q = ni * 16 + m16;
                int cw = t2 * 4 + quad;
                *reinterpret_cast<f32x4*>(
                    &exch[w * 2048 + q * 32 + ((cw ^ (q & 7)) << 2)]) = o[mi][ni];
            }
        }
        __syncthreads();
        int q = tid >> 2;
        float lsum = lbuf[q] + lbuf[64 + q] + lbuf[128 + q] + lbuf[192 + q];
        float invl = 1.0f / lsum;
#pragma unroll
        for (int half = 0; half < 2; half++) {
            int c = (tid & 3) + 4 * half;
            int off = q * 32 + (((c ^ (q & 7))) << 2);
            f32x4 v = *reinterpret_cast<const f32x4*>(&exch[off]);
            f32x4 v1 = *reinterpret_cast<const f32x4*>(&exch[2048 + off]);
            f32x4 v2 = *reinterpret_cast<const f32x4*>(&exch[4096 + off]);
            f32x4 v3 = *reinterpret_cast<const f32x4*>(&exch[6144 + off]);
            v = v + v1 + v2 + v3;
            uint2 pk;
            pk.x = pack2bf(v[0] * invl, v[1] * invl);
            pk.y = pack2bf(v[2] * invl, v[3] * invl);
            int t = qBase + q;
            *reinterpret_cast<uint2*>(
                &X[(size_t)(t * 2 + b) * C_DIM + h * DKH + rnd * 32 + c * 4]) = pk;
        }
    }
}

// ---- launch -----------------------------------------------------------------
extern "C" void kernel_launch(void* const* d_in, const int* in_sizes, int n_in,
                              void* d_out, int out_size, void* d_ws, size_t ws_size,
                              hipStream_t stream) {
    const float* query = (const float*)d_in[0];
    const float* key   = (const float*)d_in[1];
    const float* value = (const float*)d_in[2];
    const float* Wq = (const float*)d_in[3];
    const float* bq = (const float*)d_in[4];
    const float* Wk = (const float*)d_in[5];
    const float* bk = (const float*)d_in[6];
    const float* Wv = (const float*)d_in[7];
    const float* bv = (const float*)d_in[8];
    const float* Wo = (const float*)d_in[9];
    const float* bo = (const float*)d_in[10];
    float* out = (float*)d_out;

    ushort_t* qb  = (ushort_t*)d_ws;                    // [4096][1024] rows t*2+b
    ushort_t* kb  = qb  + (size_t)M_ROWS * C_DIM;
    ushort_t* vb2 = kb  + (size_t)M_ROWS * C_DIM;       // [4096][1024] rows b*T+t
    ushort_t* Wqb = vb2 + (size_t)M_ROWS * C_DIM;
    ushort_t* Wkb = Wqb + (size_t)C_DIM * C_DIM;
    ushort_t* Wvb = Wkb + (size_t)C_DIM * C_DIM;
    ushort_t* Wob = Wvb + (size_t)C_DIM * C_DIM;
    ushort_t* Qp  = Wob + (size_t)C_DIM * C_DIM;        // [4096][1024] rows t*2+b
    ushort_t* Kp  = Qp  + (size_t)M_ROWS * C_DIM;
    ushort_t* VTg = Kp  + (size_t)M_ROWS * C_DIM;       // [1024][4096] cols b*T+t
    ushort_t* Xb  = VTg + (size_t)M_ROWS * C_DIM;       // [4096][1024] rows t*2+b

    // 1) fused prep: RoPE + value perm + weight casts (one launch)
    prep_all<<<16384, 256, 0, stream>>>(query, key, value, Wq, Wk, Wv, Wo,
                                        qb, kb, vb2, Wqb, Wkb, Wvb, Wob);

    // 2) fused QKV projections: 256x64 tiles, 768 blocks = 3 blocks/CU
    qkv_gemm<<<dim3(256, 3), 512, 0, stream>>>(qb, kb, Wqb, Wkb, Wvb, vb2,
                                               bq, bk, bv, Qp, Kp, VTg);

    // 3) flash attention (V-early reorder)
    attn<<<dim3(T_SEQ / 64, B_SZ * H_HEADS), 256, 0, stream>>>(Qp, Kp, VTg, Xb);

    // 4) output projection -> fp32 d_out (r6 verified dbuf core)
    gemm_o<<<dim3(C_DIM / 64, M_ROWS / 128), 512, 0, stream>>>(Xb, Wob, bo, out);
}

// Round 9
// 225.316 us; speedup vs baseline: 1.0587x; 1.0189x over previous
//
#include <hip/hip_runtime.h>
#include <hip/hip_bf16.h>
#include <math.h>

// Problem constants (T=2048, B=2, C=1024, H=16, DK=64)
#define T_SEQ 2048
#define B_SZ 2
#define C_DIM 1024
#define H_HEADS 16
#define DKH 64
#define M_ROWS (T_SEQ * B_SZ)   // 4096 rows in (t,b) order — matches [T,B,C] flat layout

// log2(e)/8: Q projection pre-scale so softmax runs in exp2 domain
#define QSCALE 0.1803368801111204f

typedef __attribute__((ext_vector_type(8))) short bf16x8;   // 8 bf16 = 4 VGPRs (MFMA A/B frag)
typedef __attribute__((ext_vector_type(4))) float f32x4;    // MFMA C/D frag
typedef unsigned short ushort_t;

// ---- helpers ----------------------------------------------------------------

__device__ __forceinline__ ushort_t f2bf(float f) {
    unsigned u = __float_as_uint(f);
    u += 0x7fffu + ((u >> 16) & 1u);
    return (ushort_t)(u >> 16);
}

// packed f32x2 -> bf16x2
__device__ __forceinline__ unsigned pack2bf(float a, float b) {
#if __has_builtin(__builtin_amdgcn_cvt_pk_bf16_f32)
    typedef __attribute__((ext_vector_type(2))) __bf16 bf16x2_t;
    union { bf16x2_t v; unsigned u; } cv;
    cv.v = __builtin_amdgcn_cvt_pk_bf16_f32(a, b);
    return cv.u;
#else
    return (unsigned)f2bf(a) | ((unsigned)f2bf(b) << 16);
#endif
}

__device__ __forceinline__ void async_copy16(const void* g, void* l) {
    __builtin_amdgcn_global_load_lds(
        (const __attribute__((address_space(1))) void*)g,
        (__attribute__((address_space(3))) void*)l, 16, 0, 0);
}

// ---- kernel 1: fused prep — RoPE(q,k), value perm-cast, 4x weight cast ------
// blocks [0,8192): rope; [8192,12288): value perm; [12288,16384): weights
__global__ __launch_bounds__(256) void prep_all(
        const float* __restrict__ q, const float* __restrict__ k,
        const float* __restrict__ value,
        const float* __restrict__ Wq, const float* __restrict__ Wk,
        const float* __restrict__ Wv, const float* __restrict__ Wo,
        ushort_t* __restrict__ qb, ushort_t* __restrict__ kb,
        ushort_t* __restrict__ vb2,
        ushort_t* __restrict__ Wqb, ushort_t* __restrict__ Wkb,
        ushort_t* __restrict__ Wvb, ushort_t* __restrict__ Wob) {
    int bid = blockIdx.x;
    int tid = threadIdx.x;
    if (bid < 8192) {
        // RoPE on q,k + cast (rows t*2+b)
        int idx  = bid * 256 + tid;                 // [0, T*B*H*32)
        int j    = idx & 31;
        int rest = idx >> 5;                        // t*B*H + b*H + h
        int h    = rest & (H_HEADS - 1);
        int tb   = rest >> 4;                       // t*B + b
        int t    = tb >> 1;
        float inv = exp2f(-(float)j * 0.41524101186092034f);  // 10000^(-j/32)
        float ang = (float)t * inv;
        float s, c;
        sincosf(ang, &s, &c);
        int base = tb * C_DIM + h * DKH + j;
        float q1 = q[base], q2 = q[base + 32];
        float k1 = k[base], k2 = k[base + 32];
        qb[base]      = f2bf(q1 * c - q2 * s);
        qb[base + 32] = f2bf(q2 * c + q1 * s);
        kb[base]      = f2bf(k1 * c - k2 * s);
        kb[base + 32] = f2bf(k2 * c + k1 * s);
    } else if (bid < 12288) {
        // value cast with row de-interleave: out row = b*T+t
        int i   = (bid - 8192) * 256 + tid;         // float4 index over [4096][256]
        int c4  = i & 255;
        int row = i >> 8;                           // b*2048 + t
        int b   = row >> 11, t = row & 2047;
        float4 v = reinterpret_cast<const float4*>(value)[(t * 2 + b) * 256 + c4];
        ushort4 o;
        o.x = f2bf(v.x); o.y = f2bf(v.y); o.z = f2bf(v.z); o.w = f2bf(v.w);
        reinterpret_cast<ushort4*>(vb2)[i] = o;
    } else {
        // weight casts
        int r     = bid - 12288;                    // 0..4095
        int which = r >> 10;
        int i     = (r & 1023) * 256 + tid;
        const float* in = which == 0 ? Wq : which == 1 ? Wk : which == 2 ? Wv : Wo;
        ushort_t*   out = which == 0 ? Wqb : which == 1 ? Wkb : which == 2 ? Wvb : Wob;
        float4 v = reinterpret_cast<const float4*>(in)[i];
        ushort4 o;
        o.x = f2bf(v.x); o.y = f2bf(v.y); o.z = f2bf(v.z); o.w = f2bf(v.w);
        reinterpret_cast<ushort4*>(out)[i] = o;
    }
}

// ---- GEMM core: NT, 128x64 tile, 8 waves (512 thr), dbuf + vmcnt(3) ---------
// r6-verified structure (225.6 µs total): per wave 1 A-frag x 4 B-frags x 2 ks
// = 8 MFMA / 10 ds_read per K-step, double-buffered LDS, counted vmcnt(3)
// across raw s_barrier. r8's 256x64 single-buf swap was ~4 µs worse: reverted.
__device__ __forceinline__ void gemm_core(
        ushort_t* AsBase, ushort_t* BsBase,       // [2][128*64], [2][64*64]
        const ushort_t* __restrict__ A, const ushort_t* __restrict__ W,
        const float* __restrict__ bias, void* __restrict__ Cout,
        int N, int K, float scale, int rowBase, int colBase,
        bool biasRow, bool bf16out) {
    const int tid  = threadIdx.x;
    const int lane = tid & 63;
    const int w    = tid >> 6;         // 0..7
    const int m16  = lane & 15, quad = lane >> 4;
    const int r8   = lane >> 3, c8 = lane & 7;
    const int clog = c8 ^ r8;

    f32x4 acc[4];
#pragma unroll
    for (int j = 0; j < 4; j++) acc[j] = (f32x4){0.f, 0.f, 0.f, 0.f};

    // stage tile at k-offset kt into buffer buf (3 DMAs per wave)
    auto stage = [&](int buf, int kt) {
#pragma unroll
        for (int i = 0; i < 2; ++i) {
            int R = w * 16 + i * 8;
            async_copy16(A + (size_t)(rowBase + R + r8) * K + kt + clog * 8,
                         AsBase + buf * 8192 + R * 64);
        }
        {
            int R = w * 8;
            async_copy16(W + (size_t)(colBase + R + r8) * K + kt + clog * 8,
                         BsBase + buf * 4096 + R * 64);
        }
    };

    stage(0, 0);
    int cur = 0;
    for (int kt = 0; kt < K; kt += 64, cur ^= 1) {
        if (kt + 64 < K) {
            stage(cur ^ 1, kt + 64);                          // 3 more in flight
            asm volatile("s_waitcnt vmcnt(3)" ::: "memory");  // cur tile's 3 done
        } else {
            asm volatile("s_waitcnt vmcnt(0)" ::: "memory");
        }
        __builtin_amdgcn_s_barrier();       // all waves' cur parts landed
        __builtin_amdgcn_sched_barrier(0);
        const ushort_t* Asc = AsBase + cur * 8192;
        const ushort_t* Bsc = BsBase + cur * 4096;
#pragma unroll
        for (int ks = 0; ks < 2; ++ks) {
            int lc = ks * 4 + quad;
            bf16x8 af;
            {
                int R = w * 16 + m16;
                af = *reinterpret_cast<const bf16x8*>(
                    &Asc[R * 64 + ((lc ^ (R & 7)) << 3)]);
            }
            bf16x8 bfr[4];
#pragma unroll
            for (int ni = 0; ni < 4; ni++) {
                int R = ni * 16 + m16;
                bfr[ni] = *reinterpret_cast<const bf16x8*>(
                    &Bsc[R * 64 + ((lc ^ (R & 7)) << 3)]);
            }
#pragma unroll
            for (int ni = 0; ni < 4; ni++)
                acc[ni] = __builtin_amdgcn_mfma_f32_16x16x32_bf16(
                    af, bfr[ni], acc[ni], 0, 0, 0);
        }
        // all reads of cur are in regs; barrier so next prefetch may overwrite
        __builtin_amdgcn_s_barrier();
    }
#pragma unroll
    for (int ni = 0; ni < 4; ni++)
#pragma unroll
        for (int r = 0; r < 4; r++) {
            int row = rowBase + w * 16 + quad * 4 + r;
            int col = colBase + ni * 16 + m16;
            float v = (acc[ni][r] + (biasRow ? bias[row] : bias[col])) * scale;
            if (bf16out)
                ((ushort_t*)Cout)[(size_t)row * N + col] = f2bf(v);
            else
                ((float*)Cout)[(size_t)row * N + col] = v;
        }
}

// ---- kernel 2: fused QKV projections — grid (512, 3) (r6 verified) ----------
__global__ __launch_bounds__(512) void qkv_gemm(
        const ushort_t* __restrict__ qb, const ushort_t* __restrict__ kb,
        const ushort_t* __restrict__ Wqb, const ushort_t* __restrict__ Wkb,
        const ushort_t* __restrict__ Wvb, const ushort_t* __restrict__ vb2,
        const float* __restrict__ bq, const float* __restrict__ bk,
        const float* __restrict__ bv,
        ushort_t* __restrict__ Qp, ushort_t* __restrict__ Kp,
        ushort_t* __restrict__ VTg) {
    __shared__ ushort_t As[2][128 * 64];
    __shared__ ushort_t Bs[2][64 * 64];
    int z = blockIdx.y;
    const ushort_t* A; const ushort_t* W; const float* bias; ushort_t* C;
    int N, bx, by; bool biasRow; float scale;
    if (z == 0) {
        A = qb;  W = Wqb; bias = bq; C = Qp;  N = C_DIM;  biasRow = false;
        scale = QSCALE; bx = blockIdx.x & 15; by = blockIdx.x >> 4;
    } else if (z == 1) {
        A = kb;  W = Wkb; bias = bk; C = Kp;  N = C_DIM;  biasRow = false;
        scale = 1.0f;   bx = blockIdx.x & 15; by = blockIdx.x >> 4;
    } else {
        A = Wvb; W = vb2; bias = bv; C = VTg; N = M_ROWS; biasRow = true;
        scale = 1.0f;   bx = blockIdx.x & 63; by = blockIdx.x >> 6;
    }
    gemm_core(&As[0][0], &Bs[0][0], A, W, bias, C, N, C_DIM, scale,
              by * 128, bx * 64, biasRow, true);
}

// ---- kernel 3: output projection (fp32 out) (r6 verified) -------------------
__global__ __launch_bounds__(512) void gemm_o(
        const ushort_t* __restrict__ Xb, const ushort_t* __restrict__ Wob,
        const float* __restrict__ bo, float* __restrict__ out) {
    __shared__ ushort_t As[2][128 * 64];
    __shared__ ushort_t Bs[2][64 * 64];
    gemm_core(&As[0][0], &Bs[0][0], Xb, Wob, bo, out, C_DIM, C_DIM, 1.0f,
              blockIdx.y * 128, blockIdx.x * 64, false, false);
}

// ---- kernel 4: flash attention — LDS 40 KB -> 32 KB -------------------------
// Round-16: attn shows MfmaUtil 22% / VALUBusy 48% / OccupancyPercent 18% —
// latency/occupancy bound. Shrink LDS to a clean 32768:
//  - Q is staged into the V region (dead until first stageV); K(0) DMAs are
//    issued concurrently (disjoint [0,16K)) with vmcnt(4)+raw s_barrier so
//    they stay in flight through the Q prologue.
//  - epilogue: lbuf overlays the dead K region; invl is pre-loaded to regs
//    between barriers before the 32 KB exch overlay claims all of LDS.
// Main-loop schedule is the r11-verified one, bit-identical numerics.
__global__ __launch_bounds__(256) void attn(
        const ushort_t* __restrict__ Qp, const ushort_t* __restrict__ Kp,
        const ushort_t* __restrict__ VTg, ushort_t* __restrict__ X) {
    __shared__ char smem[32768];
    char*  KtC   = smem;                       // wave w: [32 key][64 dk] @ +w*4096
    char*  VTC   = smem + 16384;               // wave w: [64 dk][32 key] @ +w*4096
    ushort_t* Qt = (ushort_t*)(smem + 16384);  // prologue-only Q tile (V region)
    float* exch  = (float*)smem;               // epilogue O-exchange (32 KB)
    float* lbuf  = (float*)smem;               // epilogue l-exchange (1 KB, K region)

    const int tid  = threadIdx.x;
    const int lane = tid & 63;
    const int w    = tid >> 6;
    const int m16  = lane & 15, quad = lane >> 4;
    const int r8   = lane >> 3, c8 = lane & 7;
    const int clog = c8 ^ r8;

    // XCD-locality swizzle (bijection on 1024 block ids)
    const int lid   = blockIdx.x + blockIdx.y * 32;
    const int jj    = lid >> 3;
    const int pair  = (lid & 7) * 4 + (jj >> 5);   // b*H + h, constant per XCD group
    const int qBase = (jj & 31) * 64;
    const int b = pair >> 4, h = pair & 15;

    // hoisted loop-invariant LDS byte offsets
    const int ofA = m16 * 128 + ((quad ^ (m16 & 7)) << 4);        // ks=0, 128B rows
    const int ofB = m16 * 128 + (((4 + quad) ^ (m16 & 7)) << 4);  // ks=1
    const int sw4 = (m16 >> 1) & 3;                               // 64B-row swizzle
    const int fro = m16 * 64 + ((quad ^ sw4) << 4);               // pf/vf reads
    int pw0[2];
#pragma unroll
    for (int kt_i = 0; kt_i < 2; kt_i++)
        pw0[kt_i] = m16 * 64 + (((kt_i * 2 + (quad >> 1)) ^ sw4) << 4) + (quad & 1) * 8;
    char* PwC = KtC + w * 4096;     // P overlay on wave's own Kt quarter

    // V staging: DMA writes linearly (phys chunk = lane&3 of row lane>>2), so
    // pre-swizzle the GLOBAL source chunk: logical = phys ^ sw(row) = phys ^ ((row>>1)&3)
    const int vlc = (lane & 3) ^ ((lane >> 3) & 3);

    // split staging: K quarter (4 DMAs) / V quarter (4 DMAs)
    auto stageK = [&](int kt) {
#pragma unroll
        for (int i = 0; i < 4; ++i) {
            int key = kt + w * 32 + i * 8 + r8;
            async_copy16(Kp + (size_t)(key * 2 + b) * C_DIM + h * DKH + clog * 8,
                         KtC + w * 4096 + i * 1024);
        }
    };
    auto stageV = [&](int kt) {
#pragma unroll
        for (int i = 0; i < 4; ++i) {
            int dkr = i * 16 + (lane >> 2);
            async_copy16(VTg + (size_t)(h * DKH + dkr) * M_ROWS + b * T_SEQ + kt + w * 32 + vlc * 8,
                         VTC + w * 4096 + i * 1024);
        }
    };

    // ---- prologue: Q tile into V region; K(0) concurrent into K region ------
#pragma unroll
    for (int i = 0; i < 2; ++i) {
        int R = w * 16 + i * 8;
        async_copy16(Qp + (size_t)((qBase + R + r8) * 2 + b) * C_DIM + h * DKH + clog * 8,
                     &Qt[R * 64]);
    }
    stageK(0);                                     // disjoint region, stays in flight
    asm volatile("s_waitcnt vmcnt(4)" ::: "memory");   // Q's 2 DMAs (oldest) done
    __builtin_amdgcn_s_barrier();                  // full Qt valid across waves
    bf16x8 aq[4][2];
#pragma unroll
    for (int ni = 0; ni < 4; ni++) {
        aq[ni][0] = *reinterpret_cast<const bf16x8*>((const char*)Qt + ni * 2048 + ofA);
        aq[ni][1] = *reinterpret_cast<const bf16x8*>((const char*)Qt + ni * 2048 + ofB);
    }
    asm volatile("s_waitcnt lgkmcnt(0)" ::: "memory");
    __builtin_amdgcn_s_barrier();                  // all aq reads done everywhere
    stageV(0);                                     // may now overwrite Qt region

    float lrun[4] = {0.f, 0.f, 0.f, 0.f};
    f32x4 o[4][4];
#pragma unroll
    for (int mi = 0; mi < 4; mi++)
#pragma unroll
        for (int ni = 0; ni < 4; ni++) o[mi][ni] = (f32x4){0.f, 0.f, 0.f, 0.f};

    // ---- barrier-free main loop (r11 schedule) ------------------------------
    for (int kt = 0; kt < T_SEQ; kt += 128) {
        asm volatile("s_waitcnt vmcnt(0)" ::: "memory");
        __builtin_amdgcn_sched_barrier(0);

        // S^T = K·Q^T over wave's 32 keys x 64 q (log2 domain)
        f32x4 s[2][4];
#pragma unroll
        for (int kt_i = 0; kt_i < 2; kt_i++) {
#pragma unroll
            for (int ni = 0; ni < 4; ni++) s[kt_i][ni] = (f32x4){0.f, 0.f, 0.f, 0.f};
            bf16x8 kf0 = *reinterpret_cast<const bf16x8*>(KtC + w * 4096 + kt_i * 2048 + ofA);
            bf16x8 kf1 = *reinterpret_cast<const bf16x8*>(KtC + w * 4096 + kt_i * 2048 + ofB);
#pragma unroll
            for (int ni = 0; ni < 4; ni++) {
                s[kt_i][ni] = __builtin_amdgcn_mfma_f32_16x16x32_bf16(kf0, aq[ni][0], s[kt_i][ni], 0, 0, 0);
                s[kt_i][ni] = __builtin_amdgcn_mfma_f32_16x16x32_bf16(kf1, aq[ni][1], s[kt_i][ni], 0, 0, 0);
            }
        }

        // p = exp2(s); accumulate l; write P (bf16) into wave-private overlay
#pragma unroll
        for (int kt_i = 0; kt_i < 2; kt_i++)
#pragma unroll
            for (int ni = 0; ni < 4; ni++) {
                float p0 = __builtin_amdgcn_exp2f(s[kt_i][ni][0]);
                float p1 = __builtin_amdgcn_exp2f(s[kt_i][ni][1]);
                float p2 = __builtin_amdgcn_exp2f(s[kt_i][ni][2]);
                float p3 = __builtin_amdgcn_exp2f(s[kt_i][ni][3]);
                lrun[ni] += (p0 + p1) + (p2 + p3);
                uint2 pv;
                pv.x = pack2bf(p0, p1);
                pv.y = pack2bf(p2, p3);
                *reinterpret_cast<uint2*>(PwC + ni * 1024 + pw0[kt_i]) = pv;
            }
        asm volatile("s_waitcnt lgkmcnt(0)" ::: "memory");

        // pf/vf into regs, then quarters are dead -> prefetch next k-tile
        bf16x8 pf[4];
#pragma unroll
        for (int ni = 0; ni < 4; ni++)
            pf[ni] = *reinterpret_cast<const bf16x8*>(PwC + ni * 1024 + fro);
        bf16x8 vfr[4];
#pragma unroll
        for (int mi = 0; mi < 4; mi++)
            vfr[mi] = *reinterpret_cast<const bf16x8*>(VTC + w * 4096 + mi * 1024 + fro);
        asm volatile("s_waitcnt lgkmcnt(0)" ::: "memory");
        __builtin_amdgcn_sched_barrier(0);
        if (kt + 128 < T_SEQ) { stageK(kt + 128); stageV(kt + 128); }
        __builtin_amdgcn_sched_barrier(0);

        // O^T += V^T·P^T (pure-register; DMA for next tile flies underneath)
#pragma unroll
        for (int mi = 0; mi < 4; mi++)
#pragma unroll
            for (int ni = 0; ni < 4; ni++)
                o[mi][ni] = __builtin_amdgcn_mfma_f32_16x16x32_bf16(vfr[mi], pf[ni], o[mi][ni], 0, 0, 0);
    }

    // ---- epilogue: cross-wave l and O reduction -----------------------------
#pragma unroll
    for (int ni = 0; ni < 4; ni++) {
        lrun[ni] += __shfl_xor(lrun[ni], 16);
        lrun[ni] += __shfl_xor(lrun[ni], 32);
    }
    float lv = quad == 0 ? lrun[0] : quad == 1 ? lrun[1] : quad == 2 ? lrun[2] : lrun[3];

    __syncthreads();   // all waves out of k-loop (K region dead)
    lbuf[w * 64 + quad * 16 + m16] = lv;
    __syncthreads();   // lbuf visible
    const int qq = tid >> 2;
    const float invl = 1.0f / (lbuf[qq] + lbuf[64 + qq] + lbuf[128 + qq] + lbuf[192 + qq]);
    __syncthreads();   // lbuf reads done; exch may overwrite all 32 KB

    // O exchange in 2 rounds over the full (now-dead) 32 KB
#pragma unroll
    for (int rnd = 0; rnd < 2; rnd++) {
        if (rnd) __syncthreads();
#pragma unroll
        for (int t2 = 0; t2 < 2; t2++) {
            int mi = 2 * rnd + t2;
#pragma unroll
            for (int ni = 0; ni < 4; ni++) {
                int q = ni * 16 + m16;
                int cw = t2 * 4 + quad;
                *reinterpret_cast<f32x4*>(
                    &exch[w * 2048 + q * 32 + ((cw ^ (q & 7)) << 2)]) = o[mi][ni];
            }
        }
        __syncthreads();
#pragma unroll
        for (int half = 0; half < 2; half++) {
            int c = (tid & 3) + 4 * half;
            int off = qq * 32 + (((c ^ (qq & 7))) << 2);
            f32x4 v = *reinterpret_cast<const f32x4*>(&exch[off]);
            f32x4 v1 = *reinterpret_cast<const f32x4*>(&exch[2048 + off]);
            f32x4 v2 = *reinterpret_cast<const f32x4*>(&exch[4096 + off]);
            f32x4 v3 = *reinterpret_cast<const f32x4*>(&exch[6144 + off]);
            v = v + v1 + v2 + v3;
            uint2 pk;
            pk.x = pack2bf(v[0] * invl, v[1] * invl);
            pk.y = pack2bf(v[2] * invl, v[3] * invl);
            int t = qBase + qq;
            *reinterpret_cast<uint2*>(
                &X[(size_t)(t * 2 + b) * C_DIM + h * DKH + rnd * 32 + c * 4]) = pk;
        }
    }
}

// ---- launch -----------------------------------------------------------------
extern "C" void kernel_launch(void* const* d_in, const int* in_sizes, int n_in,
                              void* d_out, int out_size, void* d_ws, size_t ws_size,
                              hipStream_t stream) {
    const float* query = (const float*)d_in[0];
    const float* key   = (const float*)d_in[1];
    const float* value = (const float*)d_in[2];
    const float* Wq = (const float*)d_in[3];
    const float* bq = (const float*)d_in[4];
    const float* Wk = (const float*)d_in[5];
    const float* bk = (const float*)d_in[6];
    const float* Wv = (const float*)d_in[7];
    const float* bv = (const float*)d_in[8];
    const float* Wo = (const float*)d_in[9];
    const float* bo = (const float*)d_in[10];
    float* out = (float*)d_out;

    ushort_t* qb  = (ushort_t*)d_ws;                    // [4096][1024] rows t*2+b
    ushort_t* kb  = qb  + (size_t)M_ROWS * C_DIM;
    ushort_t* vb2 = kb  + (size_t)M_ROWS * C_DIM;       // [4096][1024] rows b*T+t
    ushort_t* Wqb = vb2 + (size_t)M_ROWS * C_DIM;
    ushort_t* Wkb = Wqb + (size_t)C_DIM * C_DIM;
    ushort_t* Wvb = Wkb + (size_t)C_DIM * C_DIM;
    ushort_t* Wob = Wvb + (size_t)C_DIM * C_DIM;
    ushort_t* Qp  = Wob + (size_t)C_DIM * C_DIM;        // [4096][1024] rows t*2+b
    ushort_t* Kp  = Qp  + (size_t)M_ROWS * C_DIM;
    ushort_t* VTg = Kp  + (size_t)M_ROWS * C_DIM;       // [1024][4096] cols b*T+t
    ushort_t* Xb  = VTg + (size_t)M_ROWS * C_DIM;       // [4096][1024] rows t*2+b

    // 1) fused prep: RoPE + value perm + weight casts (one launch)
    prep_all<<<16384, 256, 0, stream>>>(query, key, value, Wq, Wk, Wv, Wo,
                                        qb, kb, vb2, Wqb, Wkb, Wvb, Wob);

    // 2) fused QKV projections (r6 verified: 128x64 dbuf, 1536 blocks)
    qkv_gemm<<<dim3(512, 3), 512, 0, stream>>>(qb, kb, Wqb, Wkb, Wvb, vb2,
                                               bq, bk, bv, Qp, Kp, VTg);

    // 3) flash attention (32 KB LDS)
    attn<<<dim3(T_SEQ / 64, B_SZ * H_HEADS), 256, 0, stream>>>(Qp, Kp, VTg, Xb);

    // 4) output projection -> fp32 d_out (r6 verified dbuf core)
    gemm_o<<<dim3(C_DIM / 64, M_ROWS / 128), 512, 0, stream>>>(Xb, Wob, bo, out);
}